// Round 3
// baseline (266.921 us; speedup 1.0000x reference)
//
#include <hip/hip_runtime.h>
#include <hip/hip_bf16.h>

typedef unsigned short ushort_t;
typedef unsigned int uint_t;
typedef __attribute__((ext_vector_type(4))) float f32x4;
typedef __attribute__((ext_vector_type(8))) short short8;
typedef __attribute__((ext_vector_type(4))) short short4x;
typedef __attribute__((ext_vector_type(4))) unsigned short u16x4;
typedef __attribute__((ext_vector_type(2))) uint_t u32x2;

typedef const __attribute__((address_space(1))) unsigned char glob_t;
typedef __attribute__((address_space(3))) unsigned char lds_t;

#define S_LEN 2048
#define DM 1024
#define NH 16
#define DH 64
#define NB 2
#define BH (NB*NH)          // 32
#define MROWS (NB*S_LEN)    // 4096

__device__ __forceinline__ float bf2f(ushort_t u) {
    return __uint_as_float(((uint_t)u) << 16);
}
__device__ __forceinline__ ushort_t f2bf(float f) {
    __hip_bfloat16 h = __float2bfloat16(f);
    return *reinterpret_cast<ushort_t*>(&h);
}

// ---------------------------------------------------------------- convert
__global__ __launch_bounds__(256) void convert_all(
    const float* __restrict__ X,  const float* __restrict__ Wq,
    const float* __restrict__ Wk, const float* __restrict__ Wv,
    const float* __restrict__ Wo,
    ushort_t* __restrict__ Xb,  ushort_t* __restrict__ Wqb,
    ushort_t* __restrict__ Wkb, ushort_t* __restrict__ Wvb,
    ushort_t* __restrict__ Wob)
{
    size_t i = (size_t)blockIdx.x * 256 + threadIdx.x;
    size_t e = i * 4;
    const float* src; ushort_t* dst; size_t off;
    if (e < (size_t)MROWS * DM) { src = X; dst = Xb; off = e; }
    else {
        size_t r = e - (size_t)MROWS * DM;
        int w = (int)(r >> 20); off = r & 1048575;
        src = (w == 0) ? Wq : (w == 1) ? Wk : (w == 2) ? Wv : Wo;
        dst = (w == 0) ? Wqb : (w == 1) ? Wkb : (w == 2) ? Wvb : Wob;
    }
    float4 v = *reinterpret_cast<const float4*>(src + off);
    u16x4 o;
    o[0] = f2bf(v.x); o[1] = f2bf(v.y); o[2] = f2bf(v.z); o[3] = f2bf(v.w);
    *reinterpret_cast<u16x4*>(dst + off) = o;
}

// ---------------------------------------------------------------- rope table
__global__ __launch_bounds__(256) void rope_table_k(
    const int* __restrict__ pos, float2* __restrict__ tab)
{
    int i = blockIdx.x * 256 + threadIdx.x;   // 65536
    int s = i >> 5, f = i & 31;
    float inv = powf(10000.0f, -(float)f / 32.0f);
    float ang = (float)pos[s] * inv;
    tab[i] = make_float2(cosf(ang), sinf(ang));
}

// ---------------------------------------------------------------- GEMM
// C[m][n] = sum_k A[m][k] * W[n][k]; m97-style global_load_lds staging.
// MODE 0: QKV — z picks W/dst. z<2: fused RoPE, scatter bf16 [B,H,S,dh].
//         z==2: scatter bf16 transposed [BH][dh][S] (Vt).
// MODE 1: fp32 row-major out (O-proj)
template<int MODE>
__global__ __launch_bounds__(256) void gemm128b(
    const ushort_t* __restrict__ A,
    const ushort_t* __restrict__ W0, const ushort_t* __restrict__ W1,
    const ushort_t* __restrict__ W2,
    ushort_t* __restrict__ D0, ushort_t* __restrict__ D1,
    ushort_t* __restrict__ D2,
    float* __restrict__ Fout, const float2* __restrict__ tab)
{
    __shared__ __attribute__((aligned(16))) ushort_t As[128 * 32];
    __shared__ __attribute__((aligned(16))) ushort_t Bs[128 * 32];
    const ushort_t* W = (MODE == 1 || blockIdx.z == 0) ? W0
                        : (blockIdx.z == 1 ? W1 : W2);
    ushort_t* Dst = (blockIdx.z == 0) ? D0 : (blockIdx.z == 1) ? D1 : D2;
    int m0 = blockIdx.x * 128, n0 = blockIdx.y * 128;
    int tid = threadIdx.x, lane = tid & 63, wv = tid >> 6;
    int wm = wv >> 1, wn = wv & 1;
    int l15 = lane & 15, g = lane >> 4;

    f32x4 acc[4][4];
    for (int i = 0; i < 4; i++)
        for (int j = 0; j < 4; j++)
            acc[i][j] = (f32x4){0.f, 0.f, 0.f, 0.f};

    // staging addresses: wave wv covers rows wv*32..wv*32+31 (2 insts x 16 rows)
    int srow = wv * 32 + (lane >> 2);
    int scol = (lane & 3) * 8;
    const ushort_t* Ap = A + (size_t)(m0 + srow) * DM + scol;
    const ushort_t* Wp = W + (size_t)(n0 + srow) * DM + scol;
    lds_t* laA0 = (lds_t*)&As[wv * 1024];
    lds_t* laA1 = (lds_t*)&As[wv * 1024 + 512];
    lds_t* laB0 = (lds_t*)&Bs[wv * 1024];
    lds_t* laB1 = (lds_t*)&Bs[wv * 1024 + 512];

    for (int kk = 0; kk < DM; kk += 32) {
        __builtin_amdgcn_global_load_lds((glob_t*)(Ap + kk), laA0, 16, 0, 0);
        __builtin_amdgcn_global_load_lds((glob_t*)(Ap + 16 * DM + kk), laA1, 16, 0, 0);
        __builtin_amdgcn_global_load_lds((glob_t*)(Wp + kk), laB0, 16, 0, 0);
        __builtin_amdgcn_global_load_lds((glob_t*)(Wp + 16 * DM + kk), laB1, 16, 0, 0);
        __syncthreads();
        short8 af[4], bf[4];
        for (int i = 0; i < 4; i++)
            af[i] = *reinterpret_cast<const short8*>(
                &As[(wm * 64 + i * 16 + l15) * 32 + g * 8]);
        for (int j = 0; j < 4; j++)
            bf[j] = *reinterpret_cast<const short8*>(
                &Bs[(wn * 64 + j * 16 + l15) * 32 + g * 8]);
        __builtin_amdgcn_s_setprio(1);
        for (int i = 0; i < 4; i++)
            for (int j = 0; j < 4; j++)
                acc[i][j] = __builtin_amdgcn_mfma_f32_16x16x32_bf16(
                    af[i], bf[j], acc[i][j], 0, 0, 0);
        __builtin_amdgcn_s_setprio(0);
        __syncthreads();
    }

    for (int i = 0; i < 4; i++) {
        for (int j = 0; j < 4; j++) {
            int mbase = m0 + wm * 64 + i * 16 + g * 4;
            int n = n0 + wn * 64 + j * 16 + l15;
            if (MODE == 0) {
                int h = n >> 6, d = n & 63;
                if (blockIdx.z < 2) {
                    // fused RoPE: pairs (d even, d odd) are adjacent lanes
                    int f = d >> 1;
                    float sgn = (d & 1) ? 1.f : -1.f;
                    for (int r = 0; r < 4; r++) {
                        int m = mbase + r;
                        int b = m >> 11, s = m & 2047;
                        float v = acc[i][j][r];
                        float p = __shfl_xor(v, 1);
                        float2 cs = tab[s * 32 + f];
                        float out = v * cs.x + p * cs.y * sgn;
                        Dst[(((size_t)(b * NH + h)) * S_LEN + s) * DH + d] =
                            f2bf(out);
                    }
                } else {
                    // V: scatter transposed into [BH][64][S]
                    for (int r = 0; r < 4; r++) {
                        int m = mbase + r;
                        int b = m >> 11, s = m & 2047;
                        Dst[((size_t)(b * NH + h) * DH + d) * S_LEN + s] =
                            f2bf(acc[i][j][r]);
                    }
                }
            } else {
                for (int r = 0; r < 4; r++)
                    Fout[(size_t)(mbase + r) * DM + n] = acc[i][j][r];
            }
        }
    }
}

// ---------------------------------------------------------------- attention
// Swapped QK^T (S^T: col=q=l15, row=key=g*4+r). The S^T D-layout IS the
// A-operand layout of mfma_f32_16x16x16_bf16 -> PV = mfma(P, V) with ZERO
// redistribution shuffles. Output rows = q = g*4+r.
template<bool MASK>
__device__ __forceinline__ void attn_step64(
    int k0, int qbase, int l15, int g, int lane,
    const ushort_t* __restrict__ Kp, const ushort_t* __restrict__ Vp,
    short8 qf0, short8 qf1,
    f32x4 (&oacc)[4], float& m_run, float& l_run)
{
    // K fragments: 8 x 16B loads
    short8 kf0[4], kf1[4];
    #pragma unroll
    for (int t = 0; t < 4; t++) {
        const ushort_t* kp = &Kp[(size_t)(k0 + t * 16 + l15) * DH + g * 8];
        kf0[t] = *reinterpret_cast<const short8*>(kp);
        kf1[t] = *reinterpret_cast<const short8*>(kp + 32);
    }
    // V fragments (PV B-operand): lane(g,l15) needs Vt[dc*16+l15][k0+t*16+g*4..+3]
    short4x vb[4][4];
    #pragma unroll
    for (int t = 0; t < 4; t++)
        #pragma unroll
        for (int dc = 0; dc < 4; dc++)
            vb[t][dc] = *reinterpret_cast<const short4x*>(
                &Vp[(size_t)(dc * 16 + l15) * S_LEN + k0 + t * 16 + g * 4]);

    f32x4 st[4];
    __builtin_amdgcn_s_setprio(1);
    #pragma unroll
    for (int t = 0; t < 4; t++) {
        f32x4 z = {0.f, 0.f, 0.f, 0.f};
        z = __builtin_amdgcn_mfma_f32_16x16x32_bf16(kf0[t], qf0, z, 0, 0, 0);
        z = __builtin_amdgcn_mfma_f32_16x16x32_bf16(kf1[t], qf1, z, 0, 0, 0);
        st[t] = z;
    }
    __builtin_amdgcn_s_setprio(0);

    int q = qbase + l15;
    #pragma unroll
    for (int t = 0; t < 4; t++)
        #pragma unroll
        for (int r = 0; r < 4; r++) {
            float v = st[t][r] * 0.125f;
            if (MASK && (k0 + t * 16 + g * 4 + r) > q) v = -1e30f;
            st[t][r] = v;
        }
    float ma = fmaxf(fmaxf(st[0][0], st[0][1]), fmaxf(st[0][2], st[0][3]));
    float mb = fmaxf(fmaxf(st[1][0], st[1][1]), fmaxf(st[1][2], st[1][3]));
    float mc = fmaxf(fmaxf(st[2][0], st[2][1]), fmaxf(st[2][2], st[2][3]));
    float md = fmaxf(fmaxf(st[3][0], st[3][1]), fmaxf(st[3][2], st[3][3]));
    float m16 = fmaxf(fmaxf(ma, mb), fmaxf(mc, md));
    m16 = fmaxf(m16, __shfl_xor(m16, 16));
    m16 = fmaxf(m16, __shfl_xor(m16, 32));

    // defer-max (T13): rescale only when the running max grows materially
    if (!__all(m16 <= m_run + 8.0f)) {
        float m_new = fmaxf(m_run, m16);
        float alpha = __expf(m_run - m_new);
        m_run = m_new;
        l_run *= alpha;
        int g4 = (lane >> 4) << 2;
        float ar[4];
        #pragma unroll
        for (int r = 0; r < 4; r++) ar[r] = __shfl(alpha, g4 + r);
        #pragma unroll
        for (int dc = 0; dc < 4; dc++)
            #pragma unroll
            for (int r = 0; r < 4; r++) oacc[dc][r] *= ar[r];
    }

    float ps = 0.f;
    short4x pa[4];
    #pragma unroll
    for (int t = 0; t < 4; t++) {
        float p0 = __expf(st[t][0] - m_run);
        float p1 = __expf(st[t][1] - m_run);
        float p2 = __expf(st[t][2] - m_run);
        float p3 = __expf(st[t][3] - m_run);
        ps += (p0 + p1) + (p2 + p3);
        u32x2 w = { (uint_t)f2bf(p0) | ((uint_t)f2bf(p1) << 16),
                    (uint_t)f2bf(p2) | ((uint_t)f2bf(p3) << 16) };
        pa[t] = __builtin_bit_cast(short4x, w);
    }
    ps += __shfl_xor(ps, 16);
    ps += __shfl_xor(ps, 32);
    l_run += ps;

    __builtin_amdgcn_s_setprio(1);
    #pragma unroll
    for (int dc = 0; dc < 4; dc++)
        #pragma unroll
        for (int t = 0; t < 4; t++)
            oacc[dc] = __builtin_amdgcn_mfma_f32_16x16x16bf16_1k(
                pa[t], vb[t][dc], oacc[dc], 0, 0, 0);
    __builtin_amdgcn_s_setprio(0);
}

__global__ __launch_bounds__(256) void attn_k3(
    const ushort_t* __restrict__ Q, const ushort_t* __restrict__ K,
    const ushort_t* __restrict__ Vt, ushort_t* __restrict__ O)
{
    int wv = threadIdx.x >> 6, lane = threadIdx.x & 63;
    int l15 = lane & 15, g = lane >> 4;
    int bid = blockIdx.x;
    int qt = 31 - (bid >> 5);     // longest q-tiles dispatched first
    int bh = bid & 31;
    int qbase = qt * 64 + wv * 16;
    const ushort_t* Qp = Q + (size_t)bh * S_LEN * DH;
    const ushort_t* Kp = K + (size_t)bh * S_LEN * DH;
    const ushort_t* Vp = Vt + (size_t)bh * DH * S_LEN;

    short8 qf0 = *reinterpret_cast<const short8*>(&Qp[(qbase + l15) * DH + g * 8]);
    short8 qf1 = *reinterpret_cast<const short8*>(&Qp[(qbase + l15) * DH + 32 + g * 8]);

    f32x4 oacc[4];
    #pragma unroll
    for (int dc = 0; dc < 4; dc++) oacc[dc] = (f32x4){0.f, 0.f, 0.f, 0.f};
    float m_run = -INFINITY, l_run = 0.f;

    int full64 = qbase >> 6;
    for (int kb = 0; kb < full64; ++kb)
        attn_step64<false>(kb * 64, qbase, l15, g, lane, Kp, Vp, qf0, qf1,
                           oacc, m_run, l_run);
    attn_step64<true>(full64 * 64, qbase, l15, g, lane, Kp, Vp, qf0, qf1,
                      oacc, m_run, l_run);

    // rows q = qbase + g*4 + r need 1/l[q]; l lives at lane l15=q
    float inv = 1.0f / l_run;
    int g4 = (lane >> 4) << 2;
    float linv[4];
    #pragma unroll
    for (int r = 0; r < 4; r++) linv[r] = __shfl(inv, g4 + r);

    int b = bh >> 4, h = bh & 15;
    #pragma unroll
    for (int r = 0; r < 4; r++) {
        int q = qbase + g4 + r;
        size_t base = ((size_t)b * S_LEN + q) * DM + h * DH + l15;
        #pragma unroll
        for (int dc = 0; dc < 4; dc++)
            O[base + dc * 16] = f2bf(oacc[dc][r] * linv[r]);
    }
}

// ---------------------------------------------------------------- launch
extern "C" void kernel_launch(void* const* d_in, const int* in_sizes, int n_in,
                              void* d_out, int out_size, void* d_ws, size_t ws_size,
                              hipStream_t stream)
{
    const float* X  = (const float*)d_in[0];
    const int* pos  = (const int*)d_in[1];
    const float* qw = (const float*)d_in[2];
    const float* kw = (const float*)d_in[3];
    const float* vw = (const float*)d_in[4];
    const float* ow = (const float*)d_in[5];
    float* out = (float*)d_out;

    char* ws = (char*)d_ws;
    ushort_t* Xb   = (ushort_t*)(ws);               //  8 MB  X bf16
    ushort_t* Wqb  = (ushort_t*)(ws + 8388608);     //  2 MB
    ushort_t* Wkb  = (ushort_t*)(ws + 10485760);    //  2 MB
    ushort_t* Wvb  = (ushort_t*)(ws + 12582912);    //  2 MB
    ushort_t* Wob  = (ushort_t*)(ws + 14680064);    //  2 MB
    ushort_t* Qbh  = (ushort_t*)(ws + 16777216);    //  8 MB [BH][S][64]
    ushort_t* Kbh  = (ushort_t*)(ws + 25165824);    //  8 MB
    ushort_t* Vtb  = (ushort_t*)(ws + 41943040);    //  8 MB [BH][64][S]
    ushort_t* AttO = (ushort_t*)(ws + 50331648);    //  8 MB [B][S][1024]
    float2*   tab  = (float2*)(ws + 58720256);      //  0.5 MB

    convert_all<<<8192, 256, 0, stream>>>(X, qw, kw, vw, ow,
                                          Xb, Wqb, Wkb, Wvb, Wob);
    rope_table_k<<<256, 256, 0, stream>>>(pos, tab);
    gemm128b<0><<<dim3(32, 8, 3), 256, 0, stream>>>(
        Xb, Wqb, Wkb, Wvb, Qbh, Kbh, Vtb, nullptr, tab);
    attn_k3<<<1024, 256, 0, stream>>>(Qbh, Kbh, Vtb, AttO);
    gemm128b<1><<<dim3(32, 8, 1), 256, 0, stream>>>(
        AttO, Wob, nullptr, nullptr, nullptr, nullptr, nullptr, out, tab);
}

// Round 4
// 190.952 us; speedup vs baseline: 1.3978x; 1.3978x over previous
//
#include <hip/hip_runtime.h>
#include <hip/hip_bf16.h>

typedef unsigned short ushort_t;
typedef unsigned int uint_t;
typedef __attribute__((ext_vector_type(4))) float f32x4;
typedef __attribute__((ext_vector_type(16))) float f32x16;
typedef __attribute__((ext_vector_type(8))) short short8;
typedef __attribute__((ext_vector_type(4))) short short4x;
typedef __attribute__((ext_vector_type(4))) unsigned short u16x4;
typedef __attribute__((ext_vector_type(2))) uint_t u32x2;

typedef const __attribute__((address_space(1))) unsigned char glob_t;
typedef __attribute__((address_space(3))) unsigned char lds_t;

#define S_LEN 2048
#define DM 1024
#define NH 16
#define DH 64
#define NB 2
#define BH (NB*NH)          // 32
#define MROWS (NB*S_LEN)    // 4096

__device__ __forceinline__ float bf2f(ushort_t u) {
    return __uint_as_float(((uint_t)u) << 16);
}
__device__ __forceinline__ ushort_t f2bf(float f) {
    __hip_bfloat16 h = __float2bfloat16(f);
    return *reinterpret_cast<ushort_t*>(&h);
}

// ---------------------------------------------------------------- convert
__global__ __launch_bounds__(256) void convert_all(
    const float* __restrict__ X,  const float* __restrict__ Wq,
    const float* __restrict__ Wk, const float* __restrict__ Wv,
    const float* __restrict__ Wo,
    ushort_t* __restrict__ Xb,  ushort_t* __restrict__ Wqb,
    ushort_t* __restrict__ Wkb, ushort_t* __restrict__ Wvb,
    ushort_t* __restrict__ Wob)
{
    size_t i = (size_t)blockIdx.x * 256 + threadIdx.x;
    size_t e = i * 4;
    const float* src; ushort_t* dst; size_t off;
    if (e < (size_t)MROWS * DM) { src = X; dst = Xb; off = e; }
    else {
        size_t r = e - (size_t)MROWS * DM;
        int w = (int)(r >> 20); off = r & 1048575;
        src = (w == 0) ? Wq : (w == 1) ? Wk : (w == 2) ? Wv : Wo;
        dst = (w == 0) ? Wqb : (w == 1) ? Wkb : (w == 2) ? Wvb : Wob;
    }
    float4 v = *reinterpret_cast<const float4*>(src + off);
    u16x4 o;
    o[0] = f2bf(v.x); o[1] = f2bf(v.y); o[2] = f2bf(v.z); o[3] = f2bf(v.w);
    *reinterpret_cast<u16x4*>(dst + off) = o;
}

// ---------------------------------------------------------------- rope table
__global__ __launch_bounds__(256) void rope_table_k(
    const int* __restrict__ pos, float2* __restrict__ tab)
{
    int i = blockIdx.x * 256 + threadIdx.x;   // 65536
    int s = i >> 5, f = i & 31;
    float inv = powf(10000.0f, -(float)f / 32.0f);
    float ang = (float)pos[s] * inv;
    tab[i] = make_float2(cosf(ang), sinf(ang));
}

// ---------------------------------------------------------------- GEMM
// C[m][n] = sum_k A[m][k] * W[n][k]; m97-style global_load_lds staging.
// MODE 0: QKV — z picks W/dst. z<2: fused RoPE, scatter bf16 [B,H,S,dh].
//         z==2: scatter bf16 transposed [BH][dh][S] (Vt).
// MODE 1: fp32 row-major out (O-proj)
template<int MODE>
__global__ __launch_bounds__(256) void gemm128b(
    const ushort_t* __restrict__ A,
    const ushort_t* __restrict__ W0, const ushort_t* __restrict__ W1,
    const ushort_t* __restrict__ W2,
    ushort_t* __restrict__ D0, ushort_t* __restrict__ D1,
    ushort_t* __restrict__ D2,
    float* __restrict__ Fout, const float2* __restrict__ tab)
{
    __shared__ __attribute__((aligned(16))) ushort_t As[128 * 32];
    __shared__ __attribute__((aligned(16))) ushort_t Bs[128 * 32];
    const ushort_t* W = (MODE == 1 || blockIdx.z == 0) ? W0
                        : (blockIdx.z == 1 ? W1 : W2);
    ushort_t* Dst = (blockIdx.z == 0) ? D0 : (blockIdx.z == 1) ? D1 : D2;
    int m0 = blockIdx.x * 128, n0 = blockIdx.y * 128;
    int tid = threadIdx.x, lane = tid & 63, wv = tid >> 6;
    int wm = wv >> 1, wn = wv & 1;
    int l15 = lane & 15, g = lane >> 4;

    f32x4 acc[4][4];
    for (int i = 0; i < 4; i++)
        for (int j = 0; j < 4; j++)
            acc[i][j] = (f32x4){0.f, 0.f, 0.f, 0.f};

    int srow = wv * 32 + (lane >> 2);
    int scol = (lane & 3) * 8;
    const ushort_t* Ap = A + (size_t)(m0 + srow) * DM + scol;
    const ushort_t* Wp = W + (size_t)(n0 + srow) * DM + scol;
    lds_t* laA0 = (lds_t*)&As[wv * 1024];
    lds_t* laA1 = (lds_t*)&As[wv * 1024 + 512];
    lds_t* laB0 = (lds_t*)&Bs[wv * 1024];
    lds_t* laB1 = (lds_t*)&Bs[wv * 1024 + 512];

    for (int kk = 0; kk < DM; kk += 32) {
        __builtin_amdgcn_global_load_lds((glob_t*)(Ap + kk), laA0, 16, 0, 0);
        __builtin_amdgcn_global_load_lds((glob_t*)(Ap + 16 * DM + kk), laA1, 16, 0, 0);
        __builtin_amdgcn_global_load_lds((glob_t*)(Wp + kk), laB0, 16, 0, 0);
        __builtin_amdgcn_global_load_lds((glob_t*)(Wp + 16 * DM + kk), laB1, 16, 0, 0);
        __syncthreads();
        short8 af[4], bf[4];
        for (int i = 0; i < 4; i++)
            af[i] = *reinterpret_cast<const short8*>(
                &As[(wm * 64 + i * 16 + l15) * 32 + g * 8]);
        for (int j = 0; j < 4; j++)
            bf[j] = *reinterpret_cast<const short8*>(
                &Bs[(wn * 64 + j * 16 + l15) * 32 + g * 8]);
        __builtin_amdgcn_s_setprio(1);
        for (int i = 0; i < 4; i++)
            for (int j = 0; j < 4; j++)
                acc[i][j] = __builtin_amdgcn_mfma_f32_16x16x32_bf16(
                    af[i], bf[j], acc[i][j], 0, 0, 0);
        __builtin_amdgcn_s_setprio(0);
        __syncthreads();
    }

    for (int i = 0; i < 4; i++) {
        for (int j = 0; j < 4; j++) {
            int mbase = m0 + wm * 64 + i * 16 + g * 4;
            int n = n0 + wn * 64 + j * 16 + l15;
            if (MODE == 0) {
                int h = n >> 6, d = n & 63;
                if (blockIdx.z < 2) {
                    int f = d >> 1;
                    float sgn = (d & 1) ? 1.f : -1.f;
                    for (int r = 0; r < 4; r++) {
                        int m = mbase + r;
                        int b = m >> 11, s = m & 2047;
                        float v = acc[i][j][r];
                        float p = __shfl_xor(v, 1);
                        float2 cs = tab[s * 32 + f];
                        float out = v * cs.x + p * cs.y * sgn;
                        Dst[(((size_t)(b * NH + h)) * S_LEN + s) * DH + d] =
                            f2bf(out);
                    }
                } else {
                    for (int r = 0; r < 4; r++) {
                        int m = mbase + r;
                        int b = m >> 11, s = m & 2047;
                        Dst[((size_t)(b * NH + h) * DH + d) * S_LEN + s] =
                            f2bf(acc[i][j][r]);
                    }
                }
            } else {
                for (int r = 0; r < 4; r++)
                    Fout[(size_t)(mbase + r) * DM + n] = acc[i][j][r];
            }
        }
    }
}

// ---------------------------------------------------------------- attention
// 32x32 swapped attention. Wave = 32 q (q = qb + (lane&31)); step = 64 keys
// as two 32-key subtiles. S^T via mfma_32x32x16(K,Q): col=q=l31,
// row=key=(r&3)+8*(r>>2)+4h. PV via mfma_32x32x8(Vt,P): B-operand k-layout
// (l>>5)*4+j matches S^T regs 4kt..4kt+3 exactly -> zero-shuffle.
// Softmax in exp2 domain; only 2 shfl_xor(32) per step.
#define SCALE_L2E 0.18033688f   /* 0.125 * log2(e) */

#define LOADK(dst, kk0) do {                                                  \
    const ushort_t* kb_ = Kp + (((size_t)((kk0) + l31)) << 6) + h * 8;        \
    _Pragma("unroll") for (int ds_ = 0; ds_ < 4; ds_++) {                     \
        dst[0][ds_] = *reinterpret_cast<const short8*>(kb_ + ds_ * 16);       \
        dst[1][ds_] = *reinterpret_cast<const short8*>(kb_ + 2048 + ds_ * 16);\
    } } while (0)

#define LOADV(dst, kk0) do {                                                  \
    _Pragma("unroll") for (int db_ = 0; db_ < 2; db_++) {                     \
        const ushort_t* vr_ = Vp + (size_t)(db_ * 32 + l31) * S_LEN           \
                              + (kk0) + h * 4;                                \
        _Pragma("unroll") for (int s_ = 0; s_ < 2; s_++)                      \
        _Pragma("unroll") for (int kt_ = 0; kt_ < 4; kt_++)                   \
            dst[s_][db_][kt_] = *reinterpret_cast<const short4x*>(            \
                vr_ + s_ * 32 + kt_ * 8);                                     \
    } } while (0)

template<bool MASK>
__device__ __forceinline__ void attn_step64b(
    int k0, int qb, int l31, int h,
    const short8 (&kf)[2][4], const short4x (&vb)[2][2][4],
    const short8 (&qf)[4],
    f32x16 (&oacc)[2], float& m_run, float& l_run)
{
    f32x16 st[2];
    __builtin_amdgcn_s_setprio(1);
    #pragma unroll
    for (int s = 0; s < 2; s++) {
        f32x16 z = {0.f};
        #pragma unroll
        for (int ds = 0; ds < 4; ds++)
            z = __builtin_amdgcn_mfma_f32_32x32x16_bf16(kf[s][ds], qf[ds],
                                                        z, 0, 0, 0);
        st[s] = z;
    }
    __builtin_amdgcn_s_setprio(0);

    int q = qb + l31;
    #pragma unroll
    for (int s = 0; s < 2; s++)
        #pragma unroll
        for (int r = 0; r < 16; r++) {
            float v = st[s][r] * SCALE_L2E;
            if (MASK && (k0 + s * 32 + (r & 3) + 8 * (r >> 2) + 4 * h) > q)
                v = -1e30f;
            st[s][r] = v;
        }
    // in-lane max over 32, then combine with pair lane
    float m01 = fmaxf(st[0][0], st[0][1]);
    #pragma unroll
    for (int r = 2; r < 16; r++) m01 = fmaxf(m01, st[0][r]);
    float m1 = fmaxf(st[1][0], st[1][1]);
    #pragma unroll
    for (int r = 2; r < 16; r++) m1 = fmaxf(m1, st[1][r]);
    float m16 = fmaxf(m01, m1);
    m16 = fmaxf(m16, __shfl_xor(m16, 32));

    if (!__all(m16 <= m_run + 11.5f)) {   // defer-max (T13), exp2 domain
        float m_new = fmaxf(m_run, m16);
        float alpha = exp2f(m_run - m_new);
        m_run = m_new;
        l_run *= alpha;
        oacc[0] *= alpha;
        oacc[1] *= alpha;
    }

    float ps = 0.f;
    short4x pa[2][4];
    #pragma unroll
    for (int s = 0; s < 2; s++)
        #pragma unroll
        for (int kt = 0; kt < 4; kt++) {
            float p0 = exp2f(st[s][4 * kt + 0] - m_run);
            float p1 = exp2f(st[s][4 * kt + 1] - m_run);
            float p2 = exp2f(st[s][4 * kt + 2] - m_run);
            float p3 = exp2f(st[s][4 * kt + 3] - m_run);
            ps += (p0 + p1) + (p2 + p3);
            u32x2 w = { (uint_t)f2bf(p0) | ((uint_t)f2bf(p1) << 16),
                        (uint_t)f2bf(p2) | ((uint_t)f2bf(p3) << 16) };
            pa[s][kt] = __builtin_bit_cast(short4x, w);
        }
    ps += __shfl_xor(ps, 32);
    l_run += ps;

    __builtin_amdgcn_s_setprio(1);
    #pragma unroll
    for (int s = 0; s < 2; s++)
        #pragma unroll
        for (int kt = 0; kt < 4; kt++) {
            oacc[0] = __builtin_amdgcn_mfma_f32_32x32x8bf16_1k(
                vb[s][0][kt], pa[s][kt], oacc[0], 0, 0, 0);
            oacc[1] = __builtin_amdgcn_mfma_f32_32x32x8bf16_1k(
                vb[s][1][kt], pa[s][kt], oacc[1], 0, 0, 0);
        }
    __builtin_amdgcn_s_setprio(0);
}

__global__ __launch_bounds__(256) void attn_k4(
    const ushort_t* __restrict__ Q, const ushort_t* __restrict__ K,
    const ushort_t* __restrict__ Vt, ushort_t* __restrict__ O)
{
    int wv = threadIdx.x >> 6, lane = threadIdx.x & 63;
    int l31 = lane & 31, h = lane >> 5;
    int bid = blockIdx.x;
    // balanced pairing: first 256 blocks get bt 15..8, next 256 get bt 0..7
    int half = bid >> 8;
    int idx = (bid >> 5) & 7;
    int bt = half ? idx : 15 - idx;
    int bh = bid & 31;
    int qb = bt * 128 + wv * 32;
    const ushort_t* Qp = Q + (size_t)bh * S_LEN * DH;
    const ushort_t* Kp = K + (size_t)bh * S_LEN * DH;
    const ushort_t* Vp = Vt + (size_t)bh * DH * S_LEN;

    short8 qf[4];
    {
        const ushort_t* qp = Qp + (((size_t)(qb + l31)) << 6) + h * 8;
        #pragma unroll
        for (int ds = 0; ds < 4; ds++)
            qf[ds] = *reinterpret_cast<const short8*>(qp + ds * 16);
    }

    f32x16 oacc[2];
    oacc[0] = (f32x16){0.f};
    oacc[1] = (f32x16){0.f};
    float m_run = -INFINITY, l_run = 0.f;

    int full64 = qb >> 6;     // unmasked 64-key steps (wave-uniform)
    short8 kA[2][4], kB[2][4];
    short4x vA[2][2][4], vB[2][2][4];

    LOADK(kA, 0);
    int kb = 0;
    for (; kb + 2 <= full64; kb += 2) {
        LOADV(vA, kb * 64);
        LOADK(kB, (kb + 1) * 64);
        attn_step64b<false>(kb * 64, qb, l31, h, kA, vA, qf, oacc, m_run, l_run);
        LOADV(vB, (kb + 1) * 64);
        LOADK(kA, (kb + 2) * 64);
        attn_step64b<false>((kb + 1) * 64, qb, l31, h, kB, vB, qf, oacc, m_run, l_run);
    }
    if (kb < full64) {        // odd remainder: one full step then masked tail
        LOADV(vA, kb * 64);
        LOADK(kB, (kb + 1) * 64);
        attn_step64b<false>(kb * 64, qb, l31, h, kA, vA, qf, oacc, m_run, l_run);
        LOADV(vB, full64 * 64);
        attn_step64b<true>(full64 * 64, qb, l31, h, kB, vB, qf, oacc, m_run, l_run);
    } else {
        LOADV(vA, full64 * 64);
        attn_step64b<true>(full64 * 64, qb, l31, h, kA, vA, qf, oacc, m_run, l_run);
    }

    float inv = 1.0f / l_run;
    int b = bh >> 4, head = bh & 15;
    int q_row = qb + l31;
    size_t obase = ((size_t)b * S_LEN + q_row) * DM + head * DH;
    #pragma unroll
    for (int db = 0; db < 2; db++)
        #pragma unroll
        for (int rg = 0; rg < 4; rg++) {
            u16x4 o;
            #pragma unroll
            for (int j = 0; j < 4; j++)
                o[j] = f2bf(oacc[db][rg * 4 + j] * inv);
            *reinterpret_cast<u16x4*>(&O[obase + db * 32 + rg * 8 + h * 4]) = o;
        }
}

// ---------------------------------------------------------------- launch
extern "C" void kernel_launch(void* const* d_in, const int* in_sizes, int n_in,
                              void* d_out, int out_size, void* d_ws, size_t ws_size,
                              hipStream_t stream)
{
    const float* X  = (const float*)d_in[0];
    const int* pos  = (const int*)d_in[1];
    const float* qw = (const float*)d_in[2];
    const float* kw = (const float*)d_in[3];
    const float* vw = (const float*)d_in[4];
    const float* ow = (const float*)d_in[5];
    float* out = (float*)d_out;

    char* ws = (char*)d_ws;
    ushort_t* Xb   = (ushort_t*)(ws);               //  8 MB  X bf16
    ushort_t* Wqb  = (ushort_t*)(ws + 8388608);     //  2 MB
    ushort_t* Wkb  = (ushort_t*)(ws + 10485760);    //  2 MB
    ushort_t* Wvb  = (ushort_t*)(ws + 12582912);    //  2 MB
    ushort_t* Wob  = (ushort_t*)(ws + 14680064);    //  2 MB
    ushort_t* Qbh  = (ushort_t*)(ws + 16777216);    //  8 MB [BH][S][64]
    ushort_t* Kbh  = (ushort_t*)(ws + 25165824);    //  8 MB
    ushort_t* Vtb  = (ushort_t*)(ws + 41943040);    //  8 MB [BH][64][S]
    ushort_t* AttO = (ushort_t*)(ws + 50331648);    //  8 MB [B][S][1024]
    float2*   tab  = (float2*)(ws + 58720256);      //  0.5 MB

    convert_all<<<8192, 256, 0, stream>>>(X, qw, kw, vw, ow,
                                          Xb, Wqb, Wkb, Wvb, Wob);
    rope_table_k<<<256, 256, 0, stream>>>(pos, tab);
    gemm128b<0><<<dim3(32, 8, 3), 256, 0, stream>>>(
        Xb, Wqb, Wkb, Wvb, Qbh, Kbh, Vtb, nullptr, tab);
    attn_k4<<<512, 256, 0, stream>>>(Qbh, Kbh, Vtb, AttO);
    gemm128b<1><<<dim3(32, 8, 1), 256, 0, stream>>>(
        AttO, Wob, nullptr, nullptr, nullptr, nullptr, nullptr, out, tab);
}

// Round 5
// 168.211 us; speedup vs baseline: 1.5868x; 1.1352x over previous
//
#include <hip/hip_runtime.h>
#include <hip/hip_bf16.h>

typedef unsigned short ushort_t;
typedef unsigned int uint_t;
typedef __attribute__((ext_vector_type(4))) float f32x4;
typedef __attribute__((ext_vector_type(16))) float f32x16;
typedef __attribute__((ext_vector_type(8))) short short8;
typedef __attribute__((ext_vector_type(4))) short short4x;
typedef __attribute__((ext_vector_type(4))) unsigned short u16x4;
typedef __attribute__((ext_vector_type(2))) uint_t u32x2;

typedef const __attribute__((address_space(1))) unsigned char glob_t;
typedef __attribute__((address_space(3))) unsigned char lds_t;

#define S_LEN 2048
#define DM 1024
#define NH 16
#define DH 64
#define NB 2
#define BH (NB*NH)          // 32
#define MROWS (NB*S_LEN)    // 4096

#define SCALE_L2E 0.18033688f   /* 0.125 * log2(e) — folded into Q */

__device__ __forceinline__ float bf2f(ushort_t u) {
    return __uint_as_float(((uint_t)u) << 16);
}
__device__ __forceinline__ ushort_t f2bf(float f) {
    __hip_bfloat16 h = __float2bfloat16(f);
    return *reinterpret_cast<ushort_t*>(&h);
}

// ---------------------------------------------------------------- convert
__global__ __launch_bounds__(256) void convert_all(
    const float* __restrict__ X,  const float* __restrict__ Wq,
    const float* __restrict__ Wk, const float* __restrict__ Wv,
    const float* __restrict__ Wo,
    ushort_t* __restrict__ Xb,  ushort_t* __restrict__ Wqb,
    ushort_t* __restrict__ Wkb, ushort_t* __restrict__ Wvb,
    ushort_t* __restrict__ Wob)
{
    size_t i = (size_t)blockIdx.x * 256 + threadIdx.x;
    size_t e = i * 4;
    const float* src; ushort_t* dst; size_t off;
    if (e < (size_t)MROWS * DM) { src = X; dst = Xb; off = e; }
    else {
        size_t r = e - (size_t)MROWS * DM;
        int w = (int)(r >> 20); off = r & 1048575;
        src = (w == 0) ? Wq : (w == 1) ? Wk : (w == 2) ? Wv : Wo;
        dst = (w == 0) ? Wqb : (w == 1) ? Wkb : (w == 2) ? Wvb : Wob;
    }
    float4 v = *reinterpret_cast<const float4*>(src + off);
    u16x4 o;
    o[0] = f2bf(v.x); o[1] = f2bf(v.y); o[2] = f2bf(v.z); o[3] = f2bf(v.w);
    *reinterpret_cast<u16x4*>(dst + off) = o;
}

// ---------------------------------------------------------------- rope table
__global__ __launch_bounds__(256) void rope_table_k(
    const int* __restrict__ pos, float2* __restrict__ tab)
{
    int i = blockIdx.x * 256 + threadIdx.x;   // 65536
    int s = i >> 5, f = i & 31;
    float inv = powf(10000.0f, -(float)f / 32.0f);
    float ang = (float)pos[s] * inv;
    tab[i] = make_float2(cosf(ang), sinf(ang));
}

// ---------------------------------------------------------------- GEMM
// C[m][n] = sum_k A[m][k] * W[n][k]; m97-style global_load_lds staging.
// MODE 0: QKV — z picks W/dst. z<2: fused RoPE (z==0 also folds the
//         attention scale into Q), scatter bf16 [B,H,S,dh].
//         z==2: scatter bf16 transposed [BH][dh][S] (Vt).
// MODE 1: fp32 row-major out (O-proj)
template<int MODE>
__global__ __launch_bounds__(256) void gemm128b(
    const ushort_t* __restrict__ A,
    const ushort_t* __restrict__ W0, const ushort_t* __restrict__ W1,
    const ushort_t* __restrict__ W2,
    ushort_t* __restrict__ D0, ushort_t* __restrict__ D1,
    ushort_t* __restrict__ D2,
    float* __restrict__ Fout, const float2* __restrict__ tab)
{
    __shared__ __attribute__((aligned(16))) ushort_t As[128 * 32];
    __shared__ __attribute__((aligned(16))) ushort_t Bs[128 * 32];
    const ushort_t* W = (MODE == 1 || blockIdx.z == 0) ? W0
                        : (blockIdx.z == 1 ? W1 : W2);
    ushort_t* Dst = (blockIdx.z == 0) ? D0 : (blockIdx.z == 1) ? D1 : D2;
    int m0 = blockIdx.x * 128, n0 = blockIdx.y * 128;
    int tid = threadIdx.x, lane = tid & 63, wv = tid >> 6;
    int wm = wv >> 1, wn = wv & 1;
    int l15 = lane & 15, g = lane >> 4;

    f32x4 acc[4][4];
    for (int i = 0; i < 4; i++)
        for (int j = 0; j < 4; j++)
            acc[i][j] = (f32x4){0.f, 0.f, 0.f, 0.f};

    int srow = wv * 32 + (lane >> 2);
    int scol = (lane & 3) * 8;
    const ushort_t* Ap = A + (size_t)(m0 + srow) * DM + scol;
    const ushort_t* Wp = W + (size_t)(n0 + srow) * DM + scol;
    lds_t* laA0 = (lds_t*)&As[wv * 1024];
    lds_t* laA1 = (lds_t*)&As[wv * 1024 + 512];
    lds_t* laB0 = (lds_t*)&Bs[wv * 1024];
    lds_t* laB1 = (lds_t*)&Bs[wv * 1024 + 512];

    for (int kk = 0; kk < DM; kk += 32) {
        __builtin_amdgcn_global_load_lds((glob_t*)(Ap + kk), laA0, 16, 0, 0);
        __builtin_amdgcn_global_load_lds((glob_t*)(Ap + 16 * DM + kk), laA1, 16, 0, 0);
        __builtin_amdgcn_global_load_lds((glob_t*)(Wp + kk), laB0, 16, 0, 0);
        __builtin_amdgcn_global_load_lds((glob_t*)(Wp + 16 * DM + kk), laB1, 16, 0, 0);
        __syncthreads();
        short8 af[4], bf[4];
        for (int i = 0; i < 4; i++)
            af[i] = *reinterpret_cast<const short8*>(
                &As[(wm * 64 + i * 16 + l15) * 32 + g * 8]);
        for (int j = 0; j < 4; j++)
            bf[j] = *reinterpret_cast<const short8*>(
                &Bs[(wn * 64 + j * 16 + l15) * 32 + g * 8]);
        __builtin_amdgcn_s_setprio(1);
        for (int i = 0; i < 4; i++)
            for (int j = 0; j < 4; j++)
                acc[i][j] = __builtin_amdgcn_mfma_f32_16x16x32_bf16(
                    af[i], bf[j], acc[i][j], 0, 0, 0);
        __builtin_amdgcn_s_setprio(0);
        __syncthreads();
    }

    for (int i = 0; i < 4; i++) {
        for (int j = 0; j < 4; j++) {
            int mbase = m0 + wm * 64 + i * 16 + g * 4;
            int n = n0 + wn * 64 + j * 16 + l15;
            if (MODE == 0) {
                int h = n >> 6, d = n & 63;
                if (blockIdx.z < 2) {
                    int f = d >> 1;
                    float sgn = (d & 1) ? 1.f : -1.f;
                    float sc = (blockIdx.z == 0) ? SCALE_L2E : 1.0f;
                    for (int r = 0; r < 4; r++) {
                        int m = mbase + r;
                        int b = m >> 11, s = m & 2047;
                        float v = acc[i][j][r];
                        float p = __shfl_xor(v, 1);
                        float2 cs = tab[s * 32 + f];
                        float out = (v * cs.x + p * cs.y * sgn) * sc;
                        Dst[(((size_t)(b * NH + h)) * S_LEN + s) * DH + d] =
                            f2bf(out);
                    }
                } else {
                    for (int r = 0; r < 4; r++) {
                        int m = mbase + r;
                        int b = m >> 11, s = m & 2047;
                        Dst[((size_t)(b * NH + h) * DH + d) * S_LEN + s] =
                            f2bf(acc[i][j][r]);
                    }
                }
            } else {
                for (int r = 0; r < 4; r++)
                    Fout[(size_t)(mbase + r) * DM + n] = acc[i][j][r];
            }
        }
    }
}

// ---------------------------------------------------------------- attention
// 32x32 swapped attention, 1 wave/block (LPT-balanced fine-grained grid).
// Wave = 32 q (q = qb + (lane&31)); step = 64 keys as two 32-key subtiles.
// S^T via mfma_32x32x16(K,Q): col=q=l31, row=key=(r&3)+8*(r>>2)+4h.
// PV via mfma_32x32x8(Vt,P): B-operand k-layout matches S^T regs exactly
// -> zero-shuffle. Scores arrive pre-scaled (Q carries 0.125*log2e).
#define LOADK(dst, kk0) do {                                                  \
    const ushort_t* kb_ = Kp + (((size_t)((kk0) + l31)) << 6) + h * 8;        \
    _Pragma("unroll") for (int ds_ = 0; ds_ < 4; ds_++) {                     \
        dst[0][ds_] = *reinterpret_cast<const short8*>(kb_ + ds_ * 16);       \
        dst[1][ds_] = *reinterpret_cast<const short8*>(kb_ + 2048 + ds_ * 16);\
    } } while (0)

#define LOADV(dst, kk0) do {                                                  \
    _Pragma("unroll") for (int db_ = 0; db_ < 2; db_++) {                     \
        const ushort_t* vr_ = Vp + (size_t)(db_ * 32 + l31) * S_LEN           \
                              + (kk0) + h * 4;                                \
        _Pragma("unroll") for (int s_ = 0; s_ < 2; s_++)                      \
        _Pragma("unroll") for (int kt_ = 0; kt_ < 4; kt_++)                   \
            dst[s_][db_][kt_] = *reinterpret_cast<const short4x*>(            \
                vr_ + s_ * 32 + kt_ * 8);                                     \
    } } while (0)

template<bool MASK>
__device__ __forceinline__ void attn_step64b(
    int k0, int qb, int l31, int h,
    const short8 (&kf)[2][4], const short4x (&vb)[2][2][4],
    const short8 (&qf)[4],
    f32x16 (&oacc)[2], float& m_run, float& l_run)
{
    f32x16 st[2];
    __builtin_amdgcn_s_setprio(1);
    #pragma unroll
    for (int s = 0; s < 2; s++) {
        f32x16 z = {0.f};
        #pragma unroll
        for (int ds = 0; ds < 4; ds++)
            z = __builtin_amdgcn_mfma_f32_32x32x16_bf16(kf[s][ds], qf[ds],
                                                        z, 0, 0, 0);
        st[s] = z;
    }
    __builtin_amdgcn_s_setprio(0);

    if (MASK) {
        int q = qb + l31;
        #pragma unroll
        for (int s = 0; s < 2; s++)
            #pragma unroll
            for (int r = 0; r < 16; r++)
                if ((k0 + s * 32 + (r & 3) + 8 * (r >> 2) + 4 * h) > q)
                    st[s][r] = -1e30f;
    }
    float m0v = fmaxf(st[0][0], st[0][1]);
    #pragma unroll
    for (int r = 2; r < 16; r++) m0v = fmaxf(m0v, st[0][r]);
    float m1v = fmaxf(st[1][0], st[1][1]);
    #pragma unroll
    for (int r = 2; r < 16; r++) m1v = fmaxf(m1v, st[1][r]);
    float m16 = fmaxf(m0v, m1v);
    m16 = fmaxf(m16, __shfl_xor(m16, 32));

    if (!__all(m16 <= m_run + 11.5f)) {   // defer-max (T13), exp2 domain
        float m_new = fmaxf(m_run, m16);
        float alpha = exp2f(m_run - m_new);
        m_run = m_new;
        l_run *= alpha;
        oacc[0] *= alpha;
        oacc[1] *= alpha;
    }

    float ps = 0.f;
    short4x pa[2][4];
    #pragma unroll
    for (int s = 0; s < 2; s++)
        #pragma unroll
        for (int kt = 0; kt < 4; kt++) {
            float p0 = exp2f(st[s][4 * kt + 0] - m_run);
            float p1 = exp2f(st[s][4 * kt + 1] - m_run);
            float p2 = exp2f(st[s][4 * kt + 2] - m_run);
            float p3 = exp2f(st[s][4 * kt + 3] - m_run);
            ps += (p0 + p1) + (p2 + p3);
            u32x2 w = { (uint_t)f2bf(p0) | ((uint_t)f2bf(p1) << 16),
                        (uint_t)f2bf(p2) | ((uint_t)f2bf(p3) << 16) };
            pa[s][kt] = __builtin_bit_cast(short4x, w);
        }
    ps += __shfl_xor(ps, 32);
    l_run += ps;

    __builtin_amdgcn_s_setprio(1);
    #pragma unroll
    for (int s = 0; s < 2; s++)
        #pragma unroll
        for (int kt = 0; kt < 4; kt++) {
            oacc[0] = __builtin_amdgcn_mfma_f32_32x32x8bf16_1k(
                vb[s][0][kt], pa[s][kt], oacc[0], 0, 0, 0);
            oacc[1] = __builtin_amdgcn_mfma_f32_32x32x8bf16_1k(
                vb[s][1][kt], pa[s][kt], oacc[1], 0, 0, 0);
        }
    __builtin_amdgcn_s_setprio(0);
}

// grid = 2048 one-wave blocks. tile u descends with bid (LPT backfill);
// bh = bid&31 keeps each bh on one XCD (bh%8 == bid%8) for K/V L2 reuse.
__global__ __launch_bounds__(64) void attn_k5(
    const ushort_t* __restrict__ Q, const ushort_t* __restrict__ K,
    const ushort_t* __restrict__ Vt, ushort_t* __restrict__ O)
{
    int lane = threadIdx.x & 63;
    int l31 = lane & 31, h = lane >> 5;
    int bid = blockIdx.x;
    int u = 63 - (bid >> 5);      // 32q tile index, longest first
    int bh = bid & 31;
    int qb = u * 32;
    const ushort_t* Qp = Q + (size_t)bh * S_LEN * DH;
    const ushort_t* Kp = K + (size_t)bh * S_LEN * DH;
    const ushort_t* Vp = Vt + (size_t)bh * DH * S_LEN;

    short8 qf[4];
    {
        const ushort_t* qp = Qp + (((size_t)(qb + l31)) << 6) + h * 8;
        #pragma unroll
        for (int ds = 0; ds < 4; ds++)
            qf[ds] = *reinterpret_cast<const short8*>(qp + ds * 16);
    }

    f32x16 oacc[2];
    oacc[0] = (f32x16){0.f};
    oacc[1] = (f32x16){0.f};
    float m_run = -INFINITY, l_run = 0.f;

    int full64 = qb >> 6;     // unmasked 64-key steps (wave-uniform)
    short8 kA[2][4], kB[2][4];
    short4x vA[2][2][4], vB[2][2][4];

    LOADK(kA, 0);
    int kb = 0;
    for (; kb + 2 <= full64; kb += 2) {
        LOADV(vA, kb * 64);
        LOADK(kB, (kb + 1) * 64);
        attn_step64b<false>(kb * 64, qb, l31, h, kA, vA, qf, oacc, m_run, l_run);
        LOADV(vB, (kb + 1) * 64);
        LOADK(kA, (kb + 2) * 64);
        attn_step64b<false>((kb + 1) * 64, qb, l31, h, kB, vB, qf, oacc, m_run, l_run);
    }
    if (kb < full64) {        // odd remainder: one full step then masked tail
        LOADV(vA, kb * 64);
        LOADK(kB, (kb + 1) * 64);
        attn_step64b<false>(kb * 64, qb, l31, h, kA, vA, qf, oacc, m_run, l_run);
        LOADV(vB, full64 * 64);
        attn_step64b<true>(full64 * 64, qb, l31, h, kB, vB, qf, oacc, m_run, l_run);
    } else {
        LOADV(vA, full64 * 64);
        attn_step64b<true>(full64 * 64, qb, l31, h, kA, vA, qf, oacc, m_run, l_run);
    }

    float inv = 1.0f / l_run;
    int b = bh >> 4, head = bh & 15;
    int q_row = qb + l31;
    size_t obase = ((size_t)b * S_LEN + q_row) * DM + head * DH;
    #pragma unroll
    for (int db = 0; db < 2; db++)
        #pragma unroll
        for (int rg = 0; rg < 4; rg++) {
            u16x4 o;
            #pragma unroll
            for (int j = 0; j < 4; j++)
                o[j] = f2bf(oacc[db][rg * 4 + j] * inv);
            *reinterpret_cast<u16x4*>(&O[obase + db * 32 + rg * 8 + h * 4]) = o;
        }
}

// ---------------------------------------------------------------- launch
extern "C" void kernel_launch(void* const* d_in, const int* in_sizes, int n_in,
                              void* d_out, int out_size, void* d_ws, size_t ws_size,
                              hipStream_t stream)
{
    const float* X  = (const float*)d_in[0];
    const int* pos  = (const int*)d_in[1];
    const float* qw = (const float*)d_in[2];
    const float* kw = (const float*)d_in[3];
    const float* vw = (const float*)d_in[4];
    const float* ow = (const float*)d_in[5];
    float* out = (float*)d_out;

    char* ws = (char*)d_ws;
    ushort_t* Xb   = (ushort_t*)(ws);               //  8 MB  X bf16
    ushort_t* Wqb  = (ushort_t*)(ws + 8388608);     //  2 MB
    ushort_t* Wkb  = (ushort_t*)(ws + 10485760);    //  2 MB
    ushort_t* Wvb  = (ushort_t*)(ws + 12582912);    //  2 MB
    ushort_t* Wob  = (ushort_t*)(ws + 14680064);    //  2 MB
    ushort_t* Qbh  = (ushort_t*)(ws + 16777216);    //  8 MB [BH][S][64]
    ushort_t* Kbh  = (ushort_t*)(ws + 25165824);    //  8 MB
    ushort_t* Vtb  = (ushort_t*)(ws + 41943040);    //  8 MB [BH][64][S]
    ushort_t* AttO = (ushort_t*)(ws + 50331648);    //  8 MB [B][S][1024]
    float2*   tab  = (float2*)(ws + 58720256);      //  0.5 MB

    convert_all<<<8192, 256, 0, stream>>>(X, qw, kw, vw, ow,
                                          Xb, Wqb, Wkb, Wvb, Wob);
    rope_table_k<<<256, 256, 0, stream>>>(pos, tab);
    gemm128b<0><<<dim3(32, 8, 3), 256, 0, stream>>>(
        Xb, Wqb, Wkb, Wvb, Qbh, Kbh, Vtb, nullptr, tab);
    attn_k5<<<2048, 64, 0, stream>>>(Qbh, Kbh, Vtb, AttO);
    gemm128b<1><<<dim3(32, 8, 1), 256, 0, stream>>>(
        AttO, Wob, nullptr, nullptr, nullptr, nullptr, nullptr, out, tab);
}

// Round 7
// 143.958 us; speedup vs baseline: 1.8542x; 1.1685x over previous
//
#include <hip/hip_runtime.h>
#include <hip/hip_bf16.h>

typedef unsigned short ushort_t;
typedef unsigned int uint_t;
typedef __attribute__((ext_vector_type(4))) float f32x4;
typedef __attribute__((ext_vector_type(16))) float f32x16;
typedef __attribute__((ext_vector_type(8))) short short8;
typedef __attribute__((ext_vector_type(4))) short short4x;
typedef __attribute__((ext_vector_type(4))) unsigned short u16x4;
typedef __attribute__((ext_vector_type(2))) uint_t u32x2;

typedef const __attribute__((address_space(1))) unsigned char glob_t;
typedef __attribute__((address_space(3))) unsigned char lds_t;

#define S_LEN 2048
#define DM 1024
#define NH 16
#define DH 64
#define NB 2
#define BH (NB*NH)          // 32
#define MROWS (NB*S_LEN)    // 4096

#define SCALE_L2E 0.18033688f   /* 0.125 * log2(e) — folded into Q */

__device__ __forceinline__ float bf2f(ushort_t u) {
    return __uint_as_float(((uint_t)u) << 16);
}
__device__ __forceinline__ ushort_t f2bf(float f) {
    __hip_bfloat16 h = __float2bfloat16(f);
    return *reinterpret_cast<ushort_t*>(&h);
}

// ---------------------------------------------------------------- convert
__global__ __launch_bounds__(256) void convert_all(
    const float* __restrict__ X,  const float* __restrict__ Wq,
    const float* __restrict__ Wk, const float* __restrict__ Wv,
    const float* __restrict__ Wo,
    ushort_t* __restrict__ Xb,  ushort_t* __restrict__ Wqb,
    ushort_t* __restrict__ Wkb, ushort_t* __restrict__ Wvb,
    ushort_t* __restrict__ Wob)
{
    size_t i = (size_t)blockIdx.x * 256 + threadIdx.x;
    size_t e = i * 4;
    const float* src; ushort_t* dst; size_t off;
    if (e < (size_t)MROWS * DM) { src = X; dst = Xb; off = e; }
    else {
        size_t r = e - (size_t)MROWS * DM;
        int w = (int)(r >> 20); off = r & 1048575;
        src = (w == 0) ? Wq : (w == 1) ? Wk : (w == 2) ? Wv : Wo;
        dst = (w == 0) ? Wqb : (w == 1) ? Wkb : (w == 2) ? Wvb : Wob;
    }
    float4 v = *reinterpret_cast<const float4*>(src + off);
    u16x4 o;
    o[0] = f2bf(v.x); o[1] = f2bf(v.y); o[2] = f2bf(v.z); o[3] = f2bf(v.w);
    *reinterpret_cast<u16x4*>(dst + off) = o;
}

// ---------------------------------------------------------------- rope table
__global__ __launch_bounds__(256) void rope_table_k(
    const int* __restrict__ pos, float2* __restrict__ tab)
{
    int i = blockIdx.x * 256 + threadIdx.x;   // 65536
    int s = i >> 5, f = i & 31;
    float inv = powf(10000.0f, -(float)f / 32.0f);
    float ang = (float)pos[s] * inv;
    tab[i] = make_float2(cosf(ang), sinf(ang));
}

// ---------------------------------------------------------------- GEMM
// C[m][n] = sum_k A[m][k] * W[n][k]; m97-style global_load_lds staging.
template<int MODE>
__global__ __launch_bounds__(256) void gemm128b(
    const ushort_t* __restrict__ A,
    const ushort_t* __restrict__ W0, const ushort_t* __restrict__ W1,
    const ushort_t* __restrict__ W2,
    ushort_t* __restrict__ D0, ushort_t* __restrict__ D1,
    ushort_t* __restrict__ D2,
    float* __restrict__ Fout, const float2* __restrict__ tab)
{
    __shared__ __attribute__((aligned(16))) ushort_t As[128 * 32];
    __shared__ __attribute__((aligned(16))) ushort_t Bs[128 * 32];
    const ushort_t* W = (MODE == 1 || blockIdx.z == 0) ? W0
                        : (blockIdx.z == 1 ? W1 : W2);
    ushort_t* Dst = (blockIdx.z == 0) ? D0 : (blockIdx.z == 1) ? D1 : D2;
    int m0 = blockIdx.x * 128, n0 = blockIdx.y * 128;
    int tid = threadIdx.x, lane = tid & 63, wv = tid >> 6;
    int wm = wv >> 1, wn = wv & 1;
    int l15 = lane & 15, g = lane >> 4;

    f32x4 acc[4][4];
    for (int i = 0; i < 4; i++)
        for (int j = 0; j < 4; j++)
            acc[i][j] = (f32x4){0.f, 0.f, 0.f, 0.f};

    int srow = wv * 32 + (lane >> 2);
    int scol = (lane & 3) * 8;
    const ushort_t* Ap = A + (size_t)(m0 + srow) * DM + scol;
    const ushort_t* Wp = W + (size_t)(n0 + srow) * DM + scol;
    lds_t* laA0 = (lds_t*)&As[wv * 1024];
    lds_t* laA1 = (lds_t*)&As[wv * 1024 + 512];
    lds_t* laB0 = (lds_t*)&Bs[wv * 1024];
    lds_t* laB1 = (lds_t*)&Bs[wv * 1024 + 512];

    for (int kk = 0; kk < DM; kk += 32) {
        __builtin_amdgcn_global_load_lds((glob_t*)(Ap + kk), laA0, 16, 0, 0);
        __builtin_amdgcn_global_load_lds((glob_t*)(Ap + 16 * DM + kk), laA1, 16, 0, 0);
        __builtin_amdgcn_global_load_lds((glob_t*)(Wp + kk), laB0, 16, 0, 0);
        __builtin_amdgcn_global_load_lds((glob_t*)(Wp + 16 * DM + kk), laB1, 16, 0, 0);
        __syncthreads();
        short8 af[4], bf[4];
        for (int i = 0; i < 4; i++)
            af[i] = *reinterpret_cast<const short8*>(
                &As[(wm * 64 + i * 16 + l15) * 32 + g * 8]);
        for (int j = 0; j < 4; j++)
            bf[j] = *reinterpret_cast<const short8*>(
                &Bs[(wn * 64 + j * 16 + l15) * 32 + g * 8]);
        __builtin_amdgcn_s_setprio(1);
        for (int i = 0; i < 4; i++)
            for (int j = 0; j < 4; j++)
                acc[i][j] = __builtin_amdgcn_mfma_f32_16x16x32_bf16(
                    af[i], bf[j], acc[i][j], 0, 0, 0);
        __builtin_amdgcn_s_setprio(0);
        __syncthreads();
    }

    for (int i = 0; i < 4; i++) {
        for (int j = 0; j < 4; j++) {
            int mbase = m0 + wm * 64 + i * 16 + g * 4;
            int n = n0 + wn * 64 + j * 16 + l15;
            if (MODE == 0) {
                int h = n >> 6, d = n & 63;
                if (blockIdx.z < 2) {
                    int f = d >> 1;
                    float sgn = (d & 1) ? 1.f : -1.f;
                    float sc = (blockIdx.z == 0) ? SCALE_L2E : 1.0f;
                    for (int r = 0; r < 4; r++) {
                        int m = mbase + r;
                        int b = m >> 11, s = m & 2047;
                        float v = acc[i][j][r];
                        float p = __shfl_xor(v, 1);
                        float2 cs = tab[s * 32 + f];
                        float out = (v * cs.x + p * cs.y * sgn) * sc;
                        Dst[(((size_t)(b * NH + h)) * S_LEN + s) * DH + d] =
                            f2bf(out);
                    }
                } else {
                    for (int r = 0; r < 4; r++) {
                        int m = mbase + r;
                        int b = m >> 11, s = m & 2047;
                        Dst[((size_t)(b * NH + h) * DH + d) * S_LEN + s] =
                            f2bf(acc[i][j][r]);
                    }
                }
            } else {
                for (int r = 0; r < 4; r++)
                    Fout[(size_t)(mbase + r) * DM + n] = acc[i][j][r];
            }
        }
    }
}

// ---------------------------------------------------------------- attention
// 4-wave blocks, QBLK=128 (wave owns 32 q), KVBLK=64, double-buffered
// XOR-swizzled LDS (T2), 2-phase schedule (T3-min). Math identical to R5:
// S^T via mfma_32x32x16(K,Q); PV via mfma_32x32x8bf16_1k(Vt,P) zero-shuffle.
// LDS tiles: [64 rows][128 B], element (row,colb) stored at
// byte colb ^ ((row&7)<<4)  (pre-swizzled global source, linear gl_lds dest).
// MASK TRIGGER: k0+63 > qmin (R6 bug was qmax — missed intra-tile rows).
__global__ __launch_bounds__(256, 2) void attn_k6(
    const ushort_t* __restrict__ Q, const ushort_t* __restrict__ K,
    const ushort_t* __restrict__ Vt, ushort_t* __restrict__ O)
{
    __shared__ __attribute__((aligned(16))) ushort_t Ks[2][4096];
    __shared__ __attribute__((aligned(16))) ushort_t Vs[2][4096];

    int tid = threadIdx.x, wv = tid >> 6, lane = tid & 63;
    int l31 = lane & 31, h = lane >> 5, r7 = l31 & 7;
    int bid = blockIdx.x;
    int grp = bid >> 5;
    int u = (bid < 256) ? (15 - grp) : (grp - 8);   // constant pair-sum LPT
    int bh = bid & 31;                              // low bits -> XCD affinity
    int qb0 = u * 128;
    int qmin = qb0 + wv * 32, qmax = qmin + 31;
    int nt = 2 * u + 2;                             // key tiles for this block

    const ushort_t* Qp = Q + (size_t)bh * S_LEN * DH;
    const char* Kp = (const char*)(K + (size_t)bh * S_LEN * DH);
    const char* Vp = (const char*)(Vt + (size_t)bh * DH * S_LEN);

    short8 qf[4];
    {
        const ushort_t* qp = Qp + (((size_t)(qmin + l31)) << 6) + h * 8;
        #pragma unroll
        for (int ds = 0; ds < 4; ds++)
            qf[ds] = *reinterpret_cast<const short8*>(qp + ds * 16);
    }

    f32x16 oacc[2];
    oacc[0] = (f32x16){0.f};
    oacc[1] = (f32x16){0.f};
    float m_run = -INFINITY, l_run = 0.f;

    // --- staging: 2 chunks x (K,V) x 16B/lane; pre-swizzled global source
#define STAGE6(buf, kk0) do {                                                 \
    _Pragma("unroll") for (int c_ = 0; c_ < 2; ++c_) {                        \
        int L_ = c_ * 4096 + wv * 1024 + lane * 16;                           \
        int row_ = L_ >> 7;                                                   \
        int col_ = (L_ & 127) ^ ((row_ & 7) << 4);                            \
        __builtin_amdgcn_global_load_lds(                                     \
            (glob_t*)(Kp + (size_t)((kk0) + row_) * 128 + col_),              \
            (lds_t*)((char*)&Ks[buf][0] + c_ * 4096 + wv * 1024), 16, 0, 0);  \
        __builtin_amdgcn_global_load_lds(                                     \
            (glob_t*)(Vp + (size_t)row_ * (S_LEN * 2) + (size_t)(kk0) * 2     \
                      + col_),                                                \
            (lds_t*)((char*)&Vs[buf][0] + c_ * 4096 + wv * 1024), 16, 0, 0);  \
    } } while (0)

    STAGE6(0, 0);
    __syncthreads();

    int cur = 0;
    for (int t = 0; t < nt; ++t) {
        int k0 = t << 6;
        if (t + 1 < nt) STAGE6(cur ^ 1, (t + 1) << 6);

        if (k0 <= qmax) {
            // ---- fragments from swizzled LDS
            const char* kb = (const char*)&Ks[cur][0];
            const char* vbp = (const char*)&Vs[cur][0];
            short8 kf[2][4];
            #pragma unroll
            for (int s = 0; s < 2; s++)
                #pragma unroll
                for (int ds = 0; ds < 4; ds++)
                    kf[s][ds] = *reinterpret_cast<const short8*>(
                        kb + (s * 32 + l31) * 128 + (((h + 2 * ds) ^ r7) << 4));
            short4x vb[2][2][4];
            #pragma unroll
            for (int ss = 0; ss < 2; ss++)
                #pragma unroll
                for (int db = 0; db < 2; db++)
                    #pragma unroll
                    for (int kt = 0; kt < 4; kt++)
                        vb[ss][db][kt] = *reinterpret_cast<const short4x*>(
                            vbp + (db * 32 + l31) * 128
                            + ((((ss << 2) + kt) ^ r7) << 4) + h * 8);

            // ---- QK^T
            f32x16 st[2];
            __builtin_amdgcn_s_setprio(1);
            #pragma unroll
            for (int s = 0; s < 2; s++) {
                f32x16 z = {0.f};
                #pragma unroll
                for (int ds = 0; ds < 4; ds++)
                    z = __builtin_amdgcn_mfma_f32_32x32x16_bf16(
                        kf[s][ds], qf[ds], z, 0, 0, 0);
                st[s] = z;
            }
            __builtin_amdgcn_s_setprio(0);

            // ---- causal mask: any key in tile can exceed the wave's
            // SMALLEST q -> per-element mask needed (R6 bug: used qmax)
            if (k0 + 63 > qmin) {
                int q = qmin + l31;
                #pragma unroll
                for (int s = 0; s < 2; s++)
                    #pragma unroll
                    for (int r = 0; r < 16; r++)
                        if ((k0 + s * 32 + (r & 3) + 8 * (r >> 2) + 4 * h) > q)
                            st[s][r] = -1e30f;
            }

            // ---- online softmax (exp2 domain; scale folded into Q)
            float m0v = fmaxf(st[0][0], st[0][1]);
            #pragma unroll
            for (int r = 2; r < 16; r++) m0v = fmaxf(m0v, st[0][r]);
            float m1v = fmaxf(st[1][0], st[1][1]);
            #pragma unroll
            for (int r = 2; r < 16; r++) m1v = fmaxf(m1v, st[1][r]);
            float m16 = fmaxf(m0v, m1v);
            m16 = fmaxf(m16, __shfl_xor(m16, 32));

            if (!__all(m16 <= m_run + 11.5f)) {   // defer-max (T13)
                float m_new = fmaxf(m_run, m16);
                float alpha = exp2f(m_run - m_new);
                m_run = m_new;
                l_run *= alpha;
                oacc[0] *= alpha;
                oacc[1] *= alpha;
            }

            float ps = 0.f;
            short4x pa[2][4];
            #pragma unroll
            for (int s = 0; s < 2; s++)
                #pragma unroll
                for (int kt = 0; kt < 4; kt++) {
                    float p0 = exp2f(st[s][4 * kt + 0] - m_run);
                    float p1 = exp2f(st[s][4 * kt + 1] - m_run);
                    float p2 = exp2f(st[s][4 * kt + 2] - m_run);
                    float p3 = exp2f(st[s][4 * kt + 3] - m_run);
                    ps += (p0 + p1) + (p2 + p3);
                    u32x2 w = { (uint_t)f2bf(p0) | ((uint_t)f2bf(p1) << 16),
                                (uint_t)f2bf(p2) | ((uint_t)f2bf(p3) << 16) };
                    pa[s][kt] = __builtin_bit_cast(short4x, w);
                }
            ps += __shfl_xor(ps, 32);
            l_run += ps;

            // ---- PV (zero-shuffle: pa is already the B-operand)
            __builtin_amdgcn_s_setprio(1);
            #pragma unroll
            for (int s = 0; s < 2; s++)
                #pragma unroll
                for (int kt = 0; kt < 4; kt++) {
                    oacc[0] = __builtin_amdgcn_mfma_f32_32x32x8bf16_1k(
                        vb[s][0][kt], pa[s][kt], oacc[0], 0, 0, 0);
                    oacc[1] = __builtin_amdgcn_mfma_f32_32x32x8bf16_1k(
                        vb[s][1][kt], pa[s][kt], oacc[1], 0, 0, 0);
                }
            __builtin_amdgcn_s_setprio(0);
        }

        __syncthreads();   // drains vmcnt (stage) + lgkmcnt (reads)
        cur ^= 1;
    }

    float inv = 1.0f / l_run;
    int b = bh >> 4, head = bh & 15;
    int q_row = qmin + l31;
    size_t obase = ((size_t)b * S_LEN + q_row) * DM + head * DH;
    #pragma unroll
    for (int db = 0; db < 2; db++)
        #pragma unroll
        for (int rg = 0; rg < 4; rg++) {
            u16x4 o;
            #pragma unroll
            for (int j = 0; j < 4; j++)
                o[j] = f2bf(oacc[db][rg * 4 + j] * inv);
            *reinterpret_cast<u16x4*>(&O[obase + db * 32 + rg * 8 + h * 4]) = o;
        }
#undef STAGE6
}

// ---------------------------------------------------------------- launch
extern "C" void kernel_launch(void* const* d_in, const int* in_sizes, int n_in,
                              void* d_out, int out_size, void* d_ws, size_t ws_size,
                              hipStream_t stream)
{
    const float* X  = (const float*)d_in[0];
    const int* pos  = (const int*)d_in[1];
    const float* qw = (const float*)d_in[2];
    const float* kw = (const float*)d_in[3];
    const float* vw = (const float*)d_in[4];
    const float* ow = (const float*)d_in[5];
    float* out = (float*)d_out;

    char* ws = (char*)d_ws;
    ushort_t* Xb   = (ushort_t*)(ws);               //  8 MB  X bf16
    ushort_t* Wqb  = (ushort_t*)(ws + 8388608);     //  2 MB
    ushort_t* Wkb  = (ushort_t*)(ws + 10485760);    //  2 MB
    ushort_t* Wvb  = (ushort_t*)(ws + 12582912);    //  2 MB
    ushort_t* Wob  = (ushort_t*)(ws + 14680064);    //  2 MB
    ushort_t* Qbh  = (ushort_t*)(ws + 16777216);    //  8 MB [BH][S][64]
    ushort_t* Kbh  = (ushort_t*)(ws + 25165824);    //  8 MB
    ushort_t* Vtb  = (ushort_t*)(ws + 41943040);    //  8 MB [BH][64][S]
    ushort_t* AttO = (ushort_t*)(ws + 50331648);    //  8 MB [B][S][1024]
    float2*   tab  = (float2*)(ws + 58720256);      //  0.5 MB

    convert_all<<<8192, 256, 0, stream>>>(X, qw, kw, vw, ow,
                                          Xb, Wqb, Wkb, Wvb, Wob);
    rope_table_k<<<256, 256, 0, stream>>>(pos, tab);
    gemm128b<0><<<dim3(32, 8, 3), 256, 0, stream>>>(
        Xb, Wqb, Wkb, Wvb, Qbh, Kbh, Vtb, nullptr, tab);
    attn_k6<<<512, 256, 0, stream>>>(Qbh, Kbh, Vtb, AttO);
    gemm128b<1><<<dim3(32, 8, 1), 256, 0, stream>>>(
        AttO, Wob, nullptr, nullptr, nullptr, nullptr, nullptr, out, tab);
}